// Round 6
// baseline (264.832 us; speedup 1.0000x reference)
//
#include <hip/hip_runtime.h>
#include <hip/hip_bf16.h>
#include <cstdint>
#include <cstddef>

// TT-dense: y = relu(x @ M + b)
// x: [4096,4096] f32, M: TT(cores r=1,16,16,16,1, dims 8^4 x 8^4), out f32.
//
// Route: materialize M^T in bf16, convert x to bf16, one 4096^3 bf16 MFMA
// GEMM with fused bias+relu.
// History: R5 128^2 swizzle -> 160us; R8 256^2 8-wave 4-phase -> 135us;
//   R9 barrier-min -> 132.6; R10 read-ahead -> 130; R11 32x32 -> 150
//   (conflicts); R12 m201-quadrant -> 129.5. FOUR intra-block schedules all
//   ~130us, MfmaUtil 44-46%: per-CU MFMA (2480cyc) + LDS (2400cyc) run
//   SERIAL because all 8 waves share one barrier domain (all read together,
//   all MFMA together).
// R13: two independent 256-thread blocks per CU (tile 256x128, grid 512,
//   wave-tile 128x64 unchanged -> same per-CU LDS/MFMA totals). Separate
//   barrier domains let the HW scheduler anti-phase block A's MFMA against
//   block B's LDS bursts (m114 mechanism; what made the m97 structure work
//   at 3-4 blocks/CU). BK=32, TRIPLE-buffered 24KB pipeline (72KB/block,
//   2/CU), counted vmcnt(6), ONE barrier per K-step (128 total, fewest
//   yet). Rotation swizzle re-derived for 64B rows: pos=(h+(r>>1))&3 ->
//   each 16-lane quarter spreads 2-way over all 32 banks (same criterion
//   as the measured-0-conflict R5 scheme).

#define GM 4096
#define GN 4096
#define GK 4096
#define NT2 (GK / 32)          // 128 K-steps of 32
#define BUFS 12288             // buffer size in shorts (24 KB)

typedef __attribute__((ext_vector_type(8))) short short8_t;
typedef __attribute__((ext_vector_type(4))) float float4_t;

__device__ __forceinline__ unsigned short f2bf(float f) {
  union { float f; uint32_t u; } v; v.f = f;
  uint32_t u = v.u;
  uint32_t r = (u + 0x7fffu + ((u >> 16) & 1u)) >> 16;  // RNE
  return (unsigned short)r;
}

// ---------------------------------------------------------------------------
// Kernel 1 (512 blocks, ~4us): merge core pairs.
// G01[a01][b01][r2] = sum_r1 core0[0,a0,b0,r1] * core1[r1,a1,b1,r2]
// G23t[r2][b23][a23] = sum_r3 core2[r2,a2,b2,r3] * core3[r3,a3,b3,0]
// ---------------------------------------------------------------------------
__global__ __launch_bounds__(256) void prep_kernel(
    const float* __restrict__ c0, const float* __restrict__ c1,
    const float* __restrict__ c2, const float* __restrict__ c3,
    float* __restrict__ G01, float* __restrict__ G23t) {
  int idx = blockIdx.x * 256 + threadIdx.x;  // 0..131071
  if (idx < 65536) {
    int r2 = idx & 15;
    int b01 = (idx >> 4) & 63;
    int a01 = idx >> 10;
    int a0 = a01 >> 3, a1 = a01 & 7, b0 = b01 >> 3, b1 = b01 & 7;
    float s = 0.f;
#pragma unroll
    for (int r1 = 0; r1 < 16; ++r1)
      s += c0[(a0 * 8 + b0) * 16 + r1] * c1[((r1 * 8 + a1) * 8 + b1) * 16 + r2];
    G01[idx] = s;
  } else {
    int t = idx - 65536;  // t = r2*4096 + b23*64 + a23
    int a23 = t & 63;
    int b23 = (t >> 6) & 63;
    int r2 = t >> 12;
    int a2 = a23 >> 3, a3 = a23 & 7, b2 = b23 >> 3, b3 = b23 & 7;
    float s = 0.f;
#pragma unroll
    for (int r3 = 0; r3 < 16; ++r3)
      s += c2[((r2 * 8 + a2) * 8 + b2) * 16 + r3] * c3[(r3 * 8 + a3) * 8 + b3];
    G23t[t] = s;
  }
}

// ---------------------------------------------------------------------------
// Kernel 2 (fused, mutually independent halves).
// ---------------------------------------------------------------------------
__global__ __launch_bounds__(256) void mt_convert(
    const float* __restrict__ G01, const float* __restrict__ G23t,
    unsigned short* __restrict__ Mt,
    const float* __restrict__ x, unsigned short* __restrict__ xb) {
  int bid = blockIdx.x;
  int tid = threadIdx.x;
  if (bid < 1024) {
    int a01 = bid >> 4;
    int g = bid & 15;  // b01 = g*4 + j

    float acc[4][16];
#pragma unroll
    for (int j = 0; j < 4; ++j)
#pragma unroll
      for (int i = 0; i < 16; ++i) acc[j][i] = 0.f;

    for (int r2 = 0; r2 < 16; ++r2) {
      float gv[4];
#pragma unroll
      for (int j = 0; j < 4; ++j)
        gv[j] = G01[(a01 * 64 + g * 4 + j) * 16 + r2];  // block-uniform
      const float* src = G23t + r2 * 4096 + tid * 16;   // 64B contiguous/lane
      float4_t v0 = *(const float4_t*)(src);
      float4_t v1 = *(const float4_t*)(src + 4);
      float4_t v2 = *(const float4_t*)(src + 8);
      float4_t v3 = *(const float4_t*)(src + 12);
#pragma unroll
      for (int j = 0; j < 4; ++j) {
#pragma unroll
        for (int l = 0; l < 4; ++l) {
          acc[j][l]      += gv[j] * v0[l];
          acc[j][4 + l]  += gv[j] * v1[l];
          acc[j][8 + l]  += gv[j] * v2[l];
          acc[j][12 + l] += gv[j] * v3[l];
        }
      }
    }

    int b23 = tid >> 2;
    int a23base = (tid & 3) * 16;
#pragma unroll
    for (int j = 0; j < 4; ++j) {
      short8_t o0, o1;
#pragma unroll
      for (int i = 0; i < 8; ++i) {
        o0[i] = (short)f2bf(acc[j][i]);
        o1[i] = (short)f2bf(acc[j][8 + i]);
      }
      size_t base = (size_t)((g * 4 + j) * 64 + b23) * GK + a01 * 64 + a23base;
      *(short8_t*)(Mt + base) = o0;
      *(short8_t*)(Mt + base + 8) = o1;
    }
  } else {
    int i = ((bid - 1024) * 256 + tid) * 8;
    float4_t a = *(const float4_t*)(x + i);
    float4_t b = *(const float4_t*)(x + i + 4);
    short8_t o;
    o[0] = (short)f2bf(a[0]); o[1] = (short)f2bf(a[1]);
    o[2] = (short)f2bf(a[2]); o[3] = (short)f2bf(a[3]);
    o[4] = (short)f2bf(b[0]); o[5] = (short)f2bf(b[1]);
    o[6] = (short)f2bf(b[2]); o[7] = (short)f2bf(b[3]);
    *(short8_t*)(xb + i) = o;
  }
}

// ---------------------------------------------------------------------------
// Kernel 3: C = relu(A @ Bt^T + bias). A:[M][K] bf16, Bt:[N][K] bf16.
//
// 256x128 tile, BK=32, 4 waves (2M x 2N, wave-tile 128x64), 256 threads,
// 72 KiB LDS = 3 x 24KB buffers (A 16KB + B 8KB each). Grid 512 = 2
// independent blocks/CU (separate barrier domains -> HW anti-phases one
// block's MFMA against the other's LDS bursts).
// Per K-step t (one barrier per iter):
//   issue STAGE(t+2 -> buf[(t+2)%3])  (6 GLD)
//   ds_read 12 frags from buf[t%3] (A 8, B 4); MFMA 8x4 (setprio)
//   vmcnt(6)  [my t+1 loads landed; t+2's 6 in flight]
//   s_barrier [everyone's t+1 landed; everyone's reads of buf[t%3] done]
// Hazard proofs (R8 skeleton):
//   - overwrite: buf[(t+2)%3] == buf[(t-1)%3], whose reads completed before
//     (t-1)'s MFMA (lgkm) and barrier -> free when staged at t.
//   - landing: per-wave vmcnt(6) before the shared barrier => all waves'
//     t+1 granules landed before any wave reads them at t+1.
//   Tail: t+2>=NT2 -> no stage, vmcnt(0) at t=NT2-2.
// Rotation swizzle (64B rows, 4 chunk positions): row r, k-quarter h at
// pos p=(h+(r>>1))&3. Staging: chunk c=q*256+tid -> r=q*64+(tid>>2),
// h=((tid&3)-(tid>>3))&3 (q-independent), dest linear c*16B (GLD-legal),
// source contiguity: 4 lanes cover one 64B row (quarters permuted).
// Frag reads: p=(half+(mrow>>1))&3 (m/n-independent) -> each 16-lane
// quarter spreads 2-way over all 32 banks (the R5 zero-conflict criterion).
// XCD swizzle: 512 blocks, 16x32 block grid, 2x4 XCD regions of 8x8.
// ---------------------------------------------------------------------------
__global__ __launch_bounds__(256, 2) void gemm_bias_relu(
    const unsigned short* __restrict__ A, const unsigned short* __restrict__ Bt,
    const float* __restrict__ bias, float* __restrict__ C) {
  extern __shared__ __align__(16) unsigned short lds[];

  const int tid = threadIdx.x;
  const int bswz = blockIdx.x;
  const int xcd = bswz & 7, li = bswz >> 3;              // li 0..63
  const int row0 = ((xcd >> 2) * 8 + (li >> 3)) * 256;   // 16 M-blocks
  const int col0 = ((xcd & 3) * 8 + (li & 7)) * 128;     // 32 N-blocks
  const int wave = tid >> 6, lane = tid & 63;
  const int wm = wave >> 1, wn = wave & 1;
  const int half = lane >> 4, mrow = lane & 15;          // half = k-quarter

  // Staging: chunk c = q*256+tid; r = q*64 + (tid>>2); h q-independent.
  const int rA = tid >> 2;
  const int h0 = ((tid & 3) - (tid >> 3)) & 3;
  const unsigned short* Ap[4];
  const unsigned short* Bp[2];
#pragma unroll
  for (int q = 0; q < 4; ++q)
    Ap[q] = A + (size_t)(row0 + q * 64 + rA) * GK + h0 * 8;
#pragma unroll
  for (int q = 0; q < 2; ++q)
    Bp[q] = Bt + (size_t)(col0 + q * 64 + rA) * GK + h0 * 8;
  const int dstA = tid * 8;           // + q*2048, shorts (lane-linear)
  const int dstB = 8192 + tid * 8;    // + q*2048

#define GLD(SRC, DST)                                                  \
  __builtin_amdgcn_global_load_lds(                                    \
      (const __attribute__((address_space(1))) void*)(SRC),            \
      (__attribute__((address_space(3))) void*)(lds + (DST)), 16, 0, 0)
#define STAGE(KT, WB)                                                  \
  do {                                                                 \
    _Pragma("unroll")                                                  \
    for (int q = 0; q < 4; ++q) GLD(Ap[q] + (KT) * 32, (WB) + q * 2048 + dstA); \
    _Pragma("unroll")                                                  \
    for (int q = 0; q < 2; ++q) GLD(Bp[q] + (KT) * 32, (WB) + q * 2048 + dstB); \
  } while (0)

  // Fragment offsets (shorts): p = (half + (mrow>>1)) & 3, m/n add 512.
  const int pfrag = ((half + (mrow >> 1)) & 3) * 8;
  const int aoffB = (wm * 128 + mrow) * 32 + pfrag;
  const int boffB = 8192 + (wn * 64 + mrow) * 32 + pfrag;

  float4_t acc[8][4];
#pragma unroll
  for (int i = 0; i < 8; ++i)
#pragma unroll
    for (int n = 0; n < 4; ++n) acc[i][n] = (float4_t){0.f, 0.f, 0.f, 0.f};

  // Prologue: t0 -> buf0, t1 -> buf1; vmcnt(6): t0 landed, t1 in flight.
  STAGE(0, 0);
  STAGE(1, BUFS);
  asm volatile("s_waitcnt vmcnt(6)" ::: "memory");
  __builtin_amdgcn_s_barrier();
  __builtin_amdgcn_sched_barrier(0);

  int rb = 0;            // read base  = buf[t%3]     (shorts)
  int wb = 2 * BUFS;     // write base = buf[(t+2)%3] (shorts)
  for (int t = 0; t < NT2; ++t) {
    if (t + 2 < NT2) STAGE(t + 2, wb);

    short8_t af[8], bf[4];
#pragma unroll
    for (int m = 0; m < 8; ++m)
      af[m] = *(const short8_t*)&lds[rb + aoffB + m * 512];
#pragma unroll
    for (int n = 0; n < 4; ++n)
      bf[n] = *(const short8_t*)&lds[rb + boffB + n * 512];

    __builtin_amdgcn_s_setprio(1);
#pragma unroll
    for (int m = 0; m < 8; ++m)
#pragma unroll
      for (int n = 0; n < 4; ++n)
        acc[m][n] = __builtin_amdgcn_mfma_f32_16x16x32_bf16(
            af[m], bf[n], acc[m][n], 0, 0, 0);
    __builtin_amdgcn_s_setprio(0);

    if (t + 2 < NT2)
      asm volatile("s_waitcnt vmcnt(6)" ::: "memory");
    else if (t + 1 < NT2)
      asm volatile("s_waitcnt vmcnt(0)" ::: "memory");
    __builtin_amdgcn_s_barrier();
    __builtin_amdgcn_sched_barrier(0);

    rb = (rb == 2 * BUFS) ? 0 : rb + BUFS;
    wb = (wb == 2 * BUFS) ? 0 : wb + BUFS;
  }

#undef STAGE
#undef GLD

  // Epilogue: C/D layout col=lane&15, row=(lane>>4)*4+reg. Fuse bias+relu.
#pragma unroll
  for (int n = 0; n < 4; ++n) {
    int col = col0 + wn * 64 + n * 16 + mrow;
    float bcol = bias[col];
#pragma unroll
    for (int i = 0; i < 8; ++i) {
#pragma unroll
      for (int r = 0; r < 4; ++r) {
        int row = row0 + wm * 128 + i * 16 + half * 4 + r;
        float v = acc[i][n][r] + bcol;
        C[(size_t)row * GN + col] = v > 0.f ? v : 0.f;
      }
    }
  }
}

// ---------------------------------------------------------------------------
extern "C" void kernel_launch(void* const* d_in, const int* in_sizes, int n_in,
                              void* d_out, int out_size, void* d_ws, size_t ws_size,
                              hipStream_t stream) {
  const float* x  = (const float*)d_in[0];
  const float* c0 = (const float*)d_in[1];
  const float* c1 = (const float*)d_in[2];
  const float* c2 = (const float*)d_in[3];
  const float* c3 = (const float*)d_in[4];
  const float* b  = (const float*)d_in[5];
  float* out = (float*)d_out;

  // Workspace layout: [xb 32MB][Mt 32MB][G01 256KB][G23t 256KB]
  unsigned short* xb = (unsigned short*)d_ws;
  unsigned short* Mt = (unsigned short*)((char*)d_ws + (32u << 20));
  float* G01 = (float*)((char*)d_ws + (64u << 20));
  float* G23t = G01 + 65536;

  static bool lds_configured = false;
  if (!lds_configured) {
    (void)hipFuncSetAttribute((const void*)gemm_bias_relu,
                              hipFuncAttributeMaxDynamicSharedMemorySize,
                              3 * BUFS * 2);
    lds_configured = true;
  }

  prep_kernel<<<512, 256, 0, stream>>>(c0, c1, c2, c3, G01, G23t);
  mt_convert<<<1024 + (GM * GK) / (256 * 8), 256, 0, stream>>>(
      G01, G23t, Mt, x, xb);
  gemm_bias_relu<<<(GM / 256) * (GN / 128), 256, 3 * BUFS * 2, stream>>>(
      xb, Mt, b, out);
}

// Round 7
// 248.667 us; speedup vs baseline: 1.0650x; 1.0650x over previous
//
#include <hip/hip_runtime.h>
#include <hip/hip_bf16.h>
#include <cstdint>
#include <cstddef>

// TT-dense: y = relu(x @ M + b)
// x: [4096,4096] f32, M: TT(cores r=1,16,16,16,1, dims 8^4 x 8^4), out f32.
//
// Route: materialize M^T in bf16, convert x to bf16, one 4096^3 bf16 MFMA
// GEMM with fused bias+relu.
// History: R5 128^2 swizzle -> 160us; R8 256^2 8-wave 4-phase -> 135us;
//   R9 barrier-min -> 132.6; R10 read-ahead -> 130; R11 32x32 -> 150
//   (conflicts); R12 m201-quadrant -> 129.5; R13 2 blocks/CU -> 139.
//   SIX schedules at 130-140us, MfmaUtil 42-46%: LDS pipe and MFMA pipe
//   fully serial. R13 eliminated barrier-lockstep as the cause (separate
//   barrier domains, same result).
// R14: remove the serializers. Hypothesis: s_setprio(1) around MFMA
//   STARVES the co-resident wave's ds_read issue (prio 0) for the whole
//   cluster -> reads never drain under MFMA, and the starvation phase-locks
//   waves into read-together/MFMA-together (T5 measured -14TF on lockstep
//   GEMM, m190; only pays with role diversity). sched_barrier(0) spam
//   additionally pins compiler co-scheduling (m141: -42%). Changes vs R12:
//   (1) no setprio; (2) sched_barrier(0) only at tile boundary; (3) added
//   lgkmcnt(0) before ph1-end barrier so the hazard proofs hold without
//   scheduler pins (B0/A0-region reads provably drained before ph2's
//   STAGE_B(0,t+2) -- wait is free, reads issued a phase earlier).

#define GM 4096
#define GN 4096
#define GK 4096
#define NT (GK / 64)

typedef __attribute__((ext_vector_type(8))) short short8_t;
typedef __attribute__((ext_vector_type(4))) float float4_t;

__device__ __forceinline__ unsigned short f2bf(float f) {
  union { float f; uint32_t u; } v; v.f = f;
  uint32_t u = v.u;
  uint32_t r = (u + 0x7fffu + ((u >> 16) & 1u)) >> 16;  // RNE
  return (unsigned short)r;
}

// ---------------------------------------------------------------------------
// Kernel 1 (512 blocks, ~4us): merge core pairs.
// G01[a01][b01][r2] = sum_r1 core0[0,a0,b0,r1] * core1[r1,a1,b1,r2]
// G23t[r2][b23][a23] = sum_r3 core2[r2,a2,b2,r3] * core3[r3,a3,b3,0]
// ---------------------------------------------------------------------------
__global__ __launch_bounds__(256) void prep_kernel(
    const float* __restrict__ c0, const float* __restrict__ c1,
    const float* __restrict__ c2, const float* __restrict__ c3,
    float* __restrict__ G01, float* __restrict__ G23t) {
  int idx = blockIdx.x * 256 + threadIdx.x;  // 0..131071
  if (idx < 65536) {
    int r2 = idx & 15;
    int b01 = (idx >> 4) & 63;
    int a01 = idx >> 10;
    int a0 = a01 >> 3, a1 = a01 & 7, b0 = b01 >> 3, b1 = b01 & 7;
    float s = 0.f;
#pragma unroll
    for (int r1 = 0; r1 < 16; ++r1)
      s += c0[(a0 * 8 + b0) * 16 + r1] * c1[((r1 * 8 + a1) * 8 + b1) * 16 + r2];
    G01[idx] = s;
  } else {
    int t = idx - 65536;  // t = r2*4096 + b23*64 + a23
    int a23 = t & 63;
    int b23 = (t >> 6) & 63;
    int r2 = t >> 12;
    int a2 = a23 >> 3, a3 = a23 & 7, b2 = b23 >> 3, b3 = b23 & 7;
    float s = 0.f;
#pragma unroll
    for (int r3 = 0; r3 < 16; ++r3)
      s += c2[((r2 * 8 + a2) * 8 + b2) * 16 + r3] * c3[(r3 * 8 + a3) * 8 + b3];
    G23t[t] = s;
  }
}

// ---------------------------------------------------------------------------
// Kernel 2 (fused, mutually independent halves).
// ---------------------------------------------------------------------------
__global__ __launch_bounds__(256) void mt_convert(
    const float* __restrict__ G01, const float* __restrict__ G23t,
    unsigned short* __restrict__ Mt,
    const float* __restrict__ x, unsigned short* __restrict__ xb) {
  int bid = blockIdx.x;
  int tid = threadIdx.x;
  if (bid < 1024) {
    int a01 = bid >> 4;
    int g = bid & 15;  // b01 = g*4 + j

    float acc[4][16];
#pragma unroll
    for (int j = 0; j < 4; ++j)
#pragma unroll
      for (int i = 0; i < 16; ++i) acc[j][i] = 0.f;

    for (int r2 = 0; r2 < 16; ++r2) {
      float gv[4];
#pragma unroll
      for (int j = 0; j < 4; ++j)
        gv[j] = G01[(a01 * 64 + g * 4 + j) * 16 + r2];  // block-uniform
      const float* src = G23t + r2 * 4096 + tid * 16;   // 64B contiguous/lane
      float4_t v0 = *(const float4_t*)(src);
      float4_t v1 = *(const float4_t*)(src + 4);
      float4_t v2 = *(const float4_t*)(src + 8);
      float4_t v3 = *(const float4_t*)(src + 12);
#pragma unroll
      for (int j = 0; j < 4; ++j) {
#pragma unroll
        for (int l = 0; l < 4; ++l) {
          acc[j][l]      += gv[j] * v0[l];
          acc[j][4 + l]  += gv[j] * v1[l];
          acc[j][8 + l]  += gv[j] * v2[l];
          acc[j][12 + l] += gv[j] * v3[l];
        }
      }
    }

    int b23 = tid >> 2;
    int a23base = (tid & 3) * 16;
#pragma unroll
    for (int j = 0; j < 4; ++j) {
      short8_t o0, o1;
#pragma unroll
      for (int i = 0; i < 8; ++i) {
        o0[i] = (short)f2bf(acc[j][i]);
        o1[i] = (short)f2bf(acc[j][8 + i]);
      }
      size_t base = (size_t)((g * 4 + j) * 64 + b23) * GK + a01 * 64 + a23base;
      *(short8_t*)(Mt + base) = o0;
      *(short8_t*)(Mt + base + 8) = o1;
    }
  } else {
    int i = ((bid - 1024) * 256 + tid) * 8;
    float4_t a = *(const float4_t*)(x + i);
    float4_t b = *(const float4_t*)(x + i + 4);
    short8_t o;
    o[0] = (short)f2bf(a[0]); o[1] = (short)f2bf(a[1]);
    o[2] = (short)f2bf(a[2]); o[3] = (short)f2bf(a[3]);
    o[4] = (short)f2bf(b[0]); o[5] = (short)f2bf(b[1]);
    o[6] = (short)f2bf(b[2]); o[7] = (short)f2bf(b[3]);
    *(short8_t*)(xb + i) = o;
  }
}

// ---------------------------------------------------------------------------
// Kernel 3: C = relu(A @ Bt^T + bias). A:[M][K] bf16, Bt:[N][K] bf16.
//
// 256x256 tile, BK=64, 8 waves (2M x 4N), 512 threads, 128 KiB LDS (buf0 =
// even K-tiles, buf1 = odd). 16x16x32 MFMA, wave tile 128x64 as 4 quadrants
// of 64x32; phase = one quadrant (16 MFMA). NO setprio, NO per-phase
// sched_barrier -- compiler free to co-issue reads under MFMA:
//   ph0: RD a0f(8)+b0f(4) | stage B1(t+1)->other | bar | Q(A0,B0) | bar
//   ph1: RD b1f(4)                       | Q(A0,B1) | lgkm0 | bar
//   ph2: RD a1f(8) | stage B0(t+2)->cur  | Q(A1,B1) | lgkm0 | bar
//   ph3: stage A0,A1(t+2)->cur | Q(A1,B0) | vmcnt(6) | bar | schedbar
// Hazard proofs (pin-free form):
//   - stage B1(t+1)->other @ph0: other's B1 last read (t-1).ph1, drained by
//     (t-1).ph2's lgkm0 + barrier -- free.
//   - stage B0(t+2)->cur @ph2-start: b0f+a0f reads drained by ph1-end
//     lgkm0 + barrier (block-wide) -- free. (a0f drain also needed only by
//     ph3's A-stage; covered earlier than required.)
//   - stage A(t+2)->cur @ph3-start: a1f reads drained by ph2-end lgkm0 +
//     barrier -- free. b1f drained there too (B1-region next written at
//     (t+1).ph0).
//   - landing: vmcnt(6) at ph3-end drains through B1(t+1); 6 loads (t+2's
//     B0,A0,A1) stay in flight. Tail: kt+2>=NT -> vmcnt(0).
//   - ds_reads cannot sink past the lgkm0 asm ("memory" clobber); cannot
//     hoist above tile start (tile-end sched_barrier(0)). MFMA motion is
//     data-dep-safe (compiler-visible loads, rule #18 n/a).
// LDS rotation swizzle (R5, 0 conflicts): row r, k-half h at pos p=(h+r)&7;
// staging keeps lane-linear LDS dest, permutes global source k-offset.
// Frag reads: one base/matrix, ks=1 = ^32, frag mt/nt = +1024 each.
// XCD swizzle: 256 blocks = 1/CU; 4x8 region per XCD (bijective).
// ---------------------------------------------------------------------------
__global__ __launch_bounds__(512, 2) void gemm_bias_relu(
    const unsigned short* __restrict__ A, const unsigned short* __restrict__ Bt,
    const float* __restrict__ bias, float* __restrict__ C) {
  extern __shared__ __align__(16) unsigned short lds[];

  const int tid = threadIdx.x;
  const int bswz = blockIdx.x;
  const int xcd = bswz & 7, li = bswz >> 3;
  const int row0 = ((xcd >> 1) * 4 + (li >> 3)) * 256;
  const int col0 = ((xcd & 1) * 8 + (li & 7)) * 256;
  const int wave = tid >> 6, lane = tid & 63;
  const int wm = wave >> 2, wn = wave & 3;
  const int half = lane >> 4, mrow = lane & 15;

  // Staging invariants: chunk c = q*512+tid; r=c>>3, p=c&7, h=(p-r)&7.
  const int r0 = tid >> 3, p0 = tid & 7, h0 = (p0 - r0) & 7;
  const unsigned short* Abase = A + (size_t)(row0 + r0) * GK + h0 * 8;
  const unsigned short* Bbase = Bt + (size_t)(col0 + r0) * GK + h0 * 8;
  const int dA = r0 * 64 + p0 * 8;   // shorts; wave-linear: = tid*16 bytes
  const int dB = dA + 16384;

#define GLD(SRC, DST)                                                  \
  __builtin_amdgcn_global_load_lds(                                    \
      (const __attribute__((address_space(1))) void*)(SRC),            \
      (__attribute__((address_space(3))) void*)(lds + (DST)), 16, 0, 0)
#define STAGE_A(G, KT, BUF)                                            \
  do {                                                                 \
    const unsigned short* s_ = Abase + (size_t)(G) * 128 * GK + (KT) * 64; \
    GLD(s_, (BUF) * 32768 + (G) * 8192 + dA);                          \
    GLD(s_ + (size_t)64 * GK, (BUF) * 32768 + (G) * 8192 + dA + 4096); \
  } while (0)
#define STAGE_B(G, KT, BUF)                                            \
  do {                                                                 \
    const unsigned short* s_ = Bbase + (size_t)(G) * 128 * GK + (KT) * 64; \
    GLD(s_, (BUF) * 32768 + (G) * 8192 + dB);                          \
    GLD(s_ + (size_t)64 * GK, (BUF) * 32768 + (G) * 8192 + dB + 4096); \
  } while (0)

  // Fragment read offsets (shorts). r%8 is m-invariant -> single base,
  // ks=1 flips rotation bit2 -> ^32 shorts; frag mt/nt adds 1024.
  const int arow = wm * 128 + mrow;
  const int aoff0 = arow * 64 + ((half + arow) & 7) * 8;
  const int aoff1 = aoff0 ^ 32;
  const int brow = wn * 64 + mrow;
  const int boff0 = 16384 + brow * 64 + ((half + brow) & 7) * 8;
  const int boff1 = boff0 ^ 32;

  // RD_AH: A-half (4 mtiles MT0..MT0+3) x 2 ks -> DST[m*2+ks] (8 reads).
#define RD_AH(DST, BUF, MT0)                                                \
  do {                                                                      \
    _Pragma("unroll")                                                       \
    for (int m = 0; m < 4; ++m) {                                           \
      DST[m * 2 + 0] =                                                      \
          *(const short8_t*)&lds[(BUF)*32768 + aoff0 + ((MT0) + m) * 1024]; \
      DST[m * 2 + 1] =                                                      \
          *(const short8_t*)&lds[(BUF)*32768 + aoff1 + ((MT0) + m) * 1024]; \
    }                                                                       \
  } while (0)
  // RD_BH: B-half (2 ntiles NT0..NT0+1) x 2 ks -> DST[n*2+ks] (4 reads).
#define RD_BH(DST, BUF, NT0)                                                \
  do {                                                                      \
    _Pragma("unroll")                                                       \
    for (int n = 0; n < 2; ++n) {                                           \
      DST[n * 2 + 0] =                                                      \
          *(const short8_t*)&lds[(BUF)*32768 + boff0 + ((NT0) + n) * 1024]; \
      DST[n * 2 + 1] =                                                      \
          *(const short8_t*)&lds[(BUF)*32768 + boff1 + ((NT0) + n) * 1024]; \
    }                                                                       \
  } while (0)
  // Quadrant MFMA: 16 = 2ks x 4m x 2n, acc[MB+m][NB+n]. No setprio.
#define MFMA_H(MB, AF, NB, BF)                                              \
  do {                                                                      \
    _Pragma("unroll")                                                       \
    for (int ks = 0; ks < 2; ++ks)                                          \
      _Pragma("unroll")                                                     \
      for (int m = 0; m < 4; ++m)                                           \
        _Pragma("unroll")                                                   \
        for (int n = 0; n < 2; ++n)                                         \
          acc[(MB) + m][(NB) + n] = __builtin_amdgcn_mfma_f32_16x16x32_bf16(\
              AF[m * 2 + ks], BF[n * 2 + ks], acc[(MB) + m][(NB) + n],      \
              0, 0, 0);                                                     \
  } while (0)

#define TILE(CB, OB, KT)                                                    \
  do {                                                                      \
    /* ph0: quadrant (A0,B0) */                                             \
    RD_AH(a0f, CB, 0);                                                      \
    RD_BH(b0f, CB, 0);                                                      \
    if ((KT) + 1 < NT) STAGE_B(1, (KT) + 1, OB);                            \
    __builtin_amdgcn_s_barrier();                                           \
    MFMA_H(0, a0f, 0, b0f);                                                 \
    __builtin_amdgcn_s_barrier();                                           \
    /* ph1: quadrant (A0,B1); drain ph0/ph1 reads before ph2's B0-stage */  \
    RD_BH(b1f, CB, 2);                                                      \
    MFMA_H(0, a0f, 2, b1f);                                                 \
    asm volatile("s_waitcnt lgkmcnt(0)" ::: "memory");                      \
    __builtin_amdgcn_s_barrier();                                           \
    /* ph2: quadrant (A1,B1); drain a1f before ph3's A-stage */             \
    RD_AH(a1f, CB, 4);                                                      \
    if ((KT) + 2 < NT) STAGE_B(0, (KT) + 2, CB);                            \
    MFMA_H(4, a1f, 2, b1f);                                                 \
    asm volatile("s_waitcnt lgkmcnt(0)" ::: "memory");                      \
    __builtin_amdgcn_s_barrier();                                           \
    /* ph3: quadrant (A1,B0), no reads; stage A(t+2); counted vmcnt */      \
    if ((KT) + 2 < NT) { STAGE_A(0, (KT) + 2, CB); STAGE_A(1, (KT) + 2, CB); } \
    MFMA_H(4, a1f, 0, b0f);                                                 \
    if ((KT) + 2 < NT)                                                      \
      asm volatile("s_waitcnt vmcnt(6)" ::: "memory");                      \
    else if ((KT) + 1 < NT)                                                 \
      asm volatile("s_waitcnt vmcnt(0)" ::: "memory");                      \
    __builtin_amdgcn_s_barrier();                                           \
    __builtin_amdgcn_sched_barrier(0);                                      \
  } while (0)

  float4_t acc[8][4];
#pragma unroll
  for (int i = 0; i < 8; ++i)
#pragma unroll
    for (int n = 0; n < 4; ++n) acc[i][n] = (float4_t){0.f, 0.f, 0.f, 0.f};

  short8_t a0f[8], a1f[8], b0f[4], b1f[4];

  // Prologue: tile0 complete -> buf0 (8 loads); tile1 {B0,A0,A1} -> buf1
  // (6 loads; B1(1) staged at tile0.ph0). vmcnt(6): tile0 landed.
  STAGE_A(0, 0, 0); STAGE_A(1, 0, 0); STAGE_B(0, 0, 0); STAGE_B(1, 0, 0);
  STAGE_B(0, 1, 1); STAGE_A(0, 1, 1); STAGE_A(1, 1, 1);
  asm volatile("s_waitcnt vmcnt(6)" ::: "memory");
  __builtin_amdgcn_s_barrier();
  __builtin_amdgcn_sched_barrier(0);

  for (int kt = 0; kt < NT; kt += 2) {
    TILE(0, 1, kt);
    TILE(1, 0, kt + 1);
  }

#undef TILE
#undef MFMA_H
#undef RD_BH
#undef RD_AH
#undef STAGE_B
#undef STAGE_A
#undef GLD

  // Epilogue: C/D layout col=lane&15, row=(lane>>4)*4+reg. Fuse bias+relu.
#pragma unroll
  for (int n = 0; n < 4; ++n) {
    int col = col0 + wn * 64 + n * 16 + mrow;
    float bcol = bias[col];
#pragma unroll
    for (int i = 0; i < 8; ++i) {
#pragma unroll
      for (int r = 0; r < 4; ++r) {
        int row = row0 + wm * 128 + i * 16 + half * 4 + r;
        float v = acc[i][n][r] + bcol;
        C[(size_t)row * GN + col] = v > 0.f ? v : 0.f;
      }
    }
  }
}

// ---------------------------------------------------------------------------
extern "C" void kernel_launch(void* const* d_in, const int* in_sizes, int n_in,
                              void* d_out, int out_size, void* d_ws, size_t ws_size,
                              hipStream_t stream) {
  const float* x  = (const float*)d_in[0];
  const float* c0 = (const float*)d_in[1];
  const float* c1 = (const float*)d_in[2];
  const float* c2 = (const float*)d_in[3];
  const float* c3 = (const float*)d_in[4];
  const float* b  = (const float*)d_in[5];
  float* out = (float*)d_out;

  // Workspace layout: [xb 32MB][Mt 32MB][G01 256KB][G23t 256KB]
  unsigned short* xb = (unsigned short*)d_ws;
  unsigned short* Mt = (unsigned short*)((char*)d_ws + (32u << 20));
  float* G01 = (float*)((char*)d_ws + (64u << 20));
  float* G23t = G01 + 65536;

  static bool lds_configured = false;
  if (!lds_configured) {
    (void)hipFuncSetAttribute((const void*)gemm_bias_relu,
                              hipFuncAttributeMaxDynamicSharedMemorySize,
                              131072);
    lds_configured = true;
  }

  prep_kernel<<<512, 256, 0, stream>>>(c0, c1, c2, c3, G01, G23t);
  mt_convert<<<1024 + (GM * GK) / (256 * 8), 256, 0, stream>>>(
      G01, G23t, Mt, x, xb);
  gemm_bias_relu<<<(GM / 256) * (GN / 256), 512, 131072, stream>>>(
      xb, Mt, b, out);
}